// Round 7
// baseline (752.160 us; speedup 1.0000x reference)
//
#include <hip/hip_runtime.h>
#include <hip/hip_cooperative_groups.h>
#include <math.h>

namespace cg = cooperative_groups;

// 2-layer GCN, scalar-per-node form, zero global atomics, ONE cooperative
// kernel at HIGH occupancy (G=1024 blocks = 4/CU, 16 waves/CU — round 4's
// failure was G=256 = 1 wave/SIMD). Phases (6 grid syncs):
//   P0 hist   : per-chunk LDS histogram of fine bucket (dst>>6) -> bh[b][chunk]
//   P1 colscan: one wave per bucket row, int4 + shfl_up scan -> bh ranks, bucktot
//   P2 bscan  : block 0: exclusive scan of bucktot -> buckbase
//   P3 bin    : packed[buckbase+rank] = (src<<6)|(dst&63)   (plain stores)
//   P4 deg    : per bucket LDS int hist -> dinv = rsqrt(1+deg), g = dinv*x
//   P5 l1     : per bucket LDS float acc of g[src] -> u = dinv*h2(dinv*(acc+g))
//   P6 l2     : per bucket LDS float acc of u[src] -> out = sigmoid(...)

#define G    1024  // coop blocks; also bh row length
#define TB   256
#define MAXB 2048  // max fine buckets (LDS + bscan span)

__device__ __forceinline__ int chunk_of(int blk) {
    // consecutive chunks -> same XCD (dispatch round-robins blk%8 across XCDs)
    return ((blk & 7) * (G >> 3)) + (blk >> 3);
}

__global__ __launch_bounds__(TB, 4)
void gcn_all(const int* __restrict__ src, const int* __restrict__ dst,
             const float* __restrict__ x,
             const float* __restrict__ W1, const float* __restrict__ b1,
             const float* __restrict__ W2, const float* __restrict__ b2,
             int* __restrict__ bh, int* __restrict__ bucktot,
             int* __restrict__ buckbase, int* __restrict__ packed,
             float* __restrict__ dinv, float* __restrict__ g,
             float* __restrict__ u, float* __restrict__ out,
             int n, int e, int nb, int ec, int K)
{
    cg::grid_group grid = cg::this_grid();
    __shared__ int sh[MAXB];
    float* shf = (float*)sh;
    const int t = threadIdx.x;
    const int blk = blockIdx.x;
    const int chunk = chunk_of(blk);

    // ---- P0: histogram of fine buckets over this block's edge chunk ----
    for (int i = t; i < nb; i += TB) sh[i] = 0;
    __syncthreads();
    {
        int start = chunk * ec, end = min(e, start + ec);
        int tile = start;
        for (; tile + TB * 4 <= end; tile += TB * 4) {
            const int4 d4 = *reinterpret_cast<const int4*>(dst + tile + t * 4);
            atomicAdd(&sh[d4.x >> 6], 1);
            atomicAdd(&sh[d4.y >> 6], 1);
            atomicAdd(&sh[d4.z >> 6], 1);
            atomicAdd(&sh[d4.w >> 6], 1);
        }
        for (int i = tile + t; i < end; i += TB) atomicAdd(&sh[dst[i] >> 6], 1);
    }
    __syncthreads();
    for (int i = t; i < nb; i += TB) bh[(size_t)i * G + chunk] = sh[i];
    grid.sync();

    // ---- P1: per-row exclusive scan (one wave per bucket row) ----
    {
        const int lane = t & 63, wid = t >> 6;
        const int b = blk * 4 + wid;
        if (b < nb) {
            int4* row = reinterpret_cast<int4*>(bh + (size_t)b * G + lane * 16);
            int4 v0 = row[0], v1 = row[1], v2 = row[2], v3 = row[3];
            int s = v0.x + v0.y + v0.z + v0.w + v1.x + v1.y + v1.z + v1.w
                  + v2.x + v2.y + v2.z + v2.w + v3.x + v3.y + v3.z + v3.w;
            int inc = s;
#pragma unroll
            for (int off = 1; off < 64; off <<= 1) {
                int w = __shfl_up(inc, off, 64);
                if (lane >= off) inc += w;
            }
            int run = inc - s;  // wave-exclusive base for this lane
            int c;
            c = v0.x; v0.x = run; run += c;  c = v0.y; v0.y = run; run += c;
            c = v0.z; v0.z = run; run += c;  c = v0.w; v0.w = run; run += c;
            c = v1.x; v1.x = run; run += c;  c = v1.y; v1.y = run; run += c;
            c = v1.z; v1.z = run; run += c;  c = v1.w; v1.w = run; run += c;
            c = v2.x; v2.x = run; run += c;  c = v2.y; v2.y = run; run += c;
            c = v2.z; v2.z = run; run += c;  c = v2.w; v2.w = run; run += c;
            c = v3.x; v3.x = run; run += c;  c = v3.y; v3.y = run; run += c;
            c = v3.z; v3.z = run; run += c;  c = v3.w; v3.w = run; run += c;
            row[0] = v0; row[1] = v1; row[2] = v2; row[3] = v3;
            if (lane == 63) bucktot[b] = inc;
        }
    }
    grid.sync();

    // ---- P2: exclusive scan of bucket totals (block 0; 256 thr x 8 elems) ----
    if (blk == 0) {
        int v[8];
        int tsum = 0;
#pragma unroll
        for (int j = 0; j < 8; ++j) {
            int idx = t * 8 + j;
            int c = (idx < nb) ? bucktot[idx] : 0;
            v[j] = tsum; tsum += c;
        }
        sh[t] = tsum;
        __syncthreads();
        for (int off = 1; off < 256; off <<= 1) {
            int w = (t >= off) ? sh[t - off] : 0;
            __syncthreads();
            sh[t] += w;
            __syncthreads();
        }
        int ex = sh[t] - tsum;
#pragma unroll
        for (int j = 0; j < 8; ++j) {
            int idx = t * 8 + j;
            if (idx < nb) buckbase[idx] = ex + v[j];
        }
        if (t == 0) buckbase[nb] = e;
    }
    grid.sync();

    // ---- P3: bin edges into bucket-sorted packed[] ----
    for (int i = t; i < nb; i += TB) sh[i] = buckbase[i] + bh[(size_t)i * G + chunk];
    __syncthreads();
    {
        int start = chunk * ec, end = min(e, start + ec);
        int tile = start;
        for (; tile + TB * 4 <= end; tile += TB * 4) {
            const int4 s4 = *reinterpret_cast<const int4*>(src + tile + t * 4);
            const int4 d4 = *reinterpret_cast<const int4*>(dst + tile + t * 4);
            int p;
            p = atomicAdd(&sh[d4.x >> 6], 1); packed[p] = (s4.x << 6) | (d4.x & 63);
            p = atomicAdd(&sh[d4.y >> 6], 1); packed[p] = (s4.y << 6) | (d4.y & 63);
            p = atomicAdd(&sh[d4.z >> 6], 1); packed[p] = (s4.z << 6) | (d4.z & 63);
            p = atomicAdd(&sh[d4.w >> 6], 1); packed[p] = (s4.w << 6) | (d4.w & 63);
        }
        for (int i = tile + t; i < end; i += TB) {
            int d = dst[i], s = src[i];
            int p = atomicAdd(&sh[d >> 6], 1);
            packed[p] = (s << 6) | (d & 63);
        }
    }
    grid.sync();

    // ---- P4: degree -> dinv, g (grid-stride over buckets) ----
    for (int b = blk; b < nb; b += G) {
        __syncthreads();
        sh[t] = 0;
        __syncthreads();
        const int bank = (t & 3) << 6;
        int s0 = buckbase[b], s1 = buckbase[b + 1];
        for (int j = s0 + t; j < s1; j += TB)
            atomicAdd(&sh[bank | (packed[j] & 63)], 1);
        __syncthreads();
        if (t < 64) {
            int node = (b << 6) + t;
            if (node < n) {
                int c = sh[t] + sh[64 + t] + sh[128 + t] + sh[192 + t];
                float di = rsqrtf(1.0f + (float)c);
                dinv[node] = di;
                g[node] = di * x[node];
            }
        }
    }
    grid.sync();

    // ---- P5: layer 1 aggregate + 35-term sigmoid mix -> u ----
    for (int b = blk; b < nb; b += G) {
        __syncthreads();
        shf[t] = 0.f;
        __syncthreads();
        const int bank = (t & 3) << 6;
        int s0 = buckbase[b], s1 = buckbase[b + 1];
        for (int j = s0 + t; j < s1; j += TB) {
            int pk = packed[j];
            atomicAdd(&shf[bank | (pk & 63)], g[pk >> 6]);   // LDS float atomic
        }
        __syncthreads();
        if (t < 64) {
            int node = (b << 6) + t;
            if (node < n) {
                float s = shf[t] + shf[64 + t] + shf[128 + t] + shf[192 + t];
                float di = dinv[node];
                float tt = di * (s + g[node]);
                float h2 = 0.f;
                for (int k = 0; k < K; ++k) {
                    float z = fmaf(W1[k], tt, b1[k]);
                    h2 = fmaf(__fdividef(1.f, 1.f + __expf(-z)), W2[k], h2);
                }
                u[node] = di * h2;
            }
        }
    }
    grid.sync();

    // ---- P6: layer 2 aggregate -> out ----
    for (int b = blk; b < nb; b += G) {
        __syncthreads();
        shf[t] = 0.f;
        __syncthreads();
        const int bank = (t & 3) << 6;
        int s0 = buckbase[b], s1 = buckbase[b + 1];
        for (int j = s0 + t; j < s1; j += TB) {
            int pk = packed[j];
            atomicAdd(&shf[bank | (pk & 63)], u[pk >> 6]);
        }
        __syncthreads();
        if (t < 64) {
            int node = (b << 6) + t;
            if (node < n) {
                float s = shf[t] + shf[64 + t] + shf[128 + t] + shf[192 + t];
                float z = fmaf(dinv[node], s + u[node], b2[0]);
                out[node] = __fdividef(1.f, 1.f + __expf(-z));
            }
        }
    }
}

// ---------------- fallback (round-1 atomic path, 3n floats) ----------------
__global__ void f_init(float* __restrict__ deg, int n) {
    int i = blockIdx.x * 256 + threadIdx.x;
    if (i < n) deg[i] = 1.0f;
}
__global__ void f_degree(const int* __restrict__ dst, float* __restrict__ deg, int e) {
    int i = blockIdx.x * 256 + threadIdx.x;
    if (i < e) atomicAdd(&deg[dst[i]], 1.0f);
}
__global__ void f_node1(const float* __restrict__ x, float* dd,
                        float* __restrict__ g, float* __restrict__ s, int n) {
    int i = blockIdx.x * 256 + threadIdx.x;
    if (i < n) {
        float di = rsqrtf(dd[i]);
        dd[i] = di;
        float gi = di * x[i];
        g[i] = gi; s[i] = gi;
    }
}
__global__ void f_scatter(const int* __restrict__ src, const int* __restrict__ dst,
                          const float* __restrict__ g, float* __restrict__ s, int e) {
    int i = blockIdx.x * 256 + threadIdx.x;
    if (i < e) atomicAdd(&s[dst[i]], g[src[i]]);
}
__global__ void f_node2(const float* __restrict__ dinv, const float* s,
                        const float* __restrict__ W1, const float* __restrict__ b1,
                        const float* __restrict__ W2, float* u, float* r, int n, int K) {
    int i = blockIdx.x * 256 + threadIdx.x;
    if (i < n) {
        float tt = dinv[i] * s[i];
        float h2 = 0.f;
        for (int k = 0; k < K; ++k) {
            float z = fmaf(W1[k], tt, b1[k]);
            h2 = fmaf(__fdividef(1.f, 1.f + __expf(-z)), W2[k], h2);
        }
        float ui = dinv[i] * h2;
        u[i] = ui; r[i] = ui;
    }
}
__global__ void f_out(const float* __restrict__ dinv, const float* __restrict__ r,
                      const float* __restrict__ b2, float* __restrict__ out, int n) {
    int i = blockIdx.x * 256 + threadIdx.x;
    if (i < n) {
        float z = fmaf(dinv[i], r[i], b2[0]);
        out[i] = __fdividef(1.f, 1.f + __expf(-z));
    }
}

extern "C" void kernel_launch(void* const* d_in, const int* in_sizes, int n_in,
                              void* d_out, int out_size, void* d_ws, size_t ws_size,
                              hipStream_t stream) {
    const float* x  = (const float*)d_in[0];
    const int*   ei = (const int*)d_in[1];
    const float* W1 = (const float*)d_in[2];
    const float* b1 = (const float*)d_in[3];
    const float* W2 = (const float*)d_in[4];
    const float* b2 = (const float*)d_in[5];

    const int n = in_sizes[0];
    const int e = in_sizes[1] / 2;
    const int K = in_sizes[2];
    const int* src = ei;
    const int* dst = ei + e;
    float* out = (float*)d_out;

    const int nb = (n + 63) >> 6;                    // fine buckets (64 nodes)
    const int ec = (((e + G - 1) / G) + 3) & ~3;     // edges/chunk, mult of 4

    // ws: bh[nb*G] bucktot[nb] buckbase[nb+1] packed[e] dinv[n] g[n] u[n]
    size_t need = ((size_t)nb * G + 2 * (size_t)nb + 1 + (size_t)e + 3 * (size_t)n) * 4;

    if (nb <= MAXB && ws_size >= need) {
        int* bh       = (int*)d_ws;
        int* bucktot  = bh + (size_t)nb * G;
        int* buckbase = bucktot + nb;
        int* packed   = buckbase + nb + 1;
        float* dinv   = (float*)(packed + e);
        float* g      = dinv + n;
        float* u      = g + n;

        void* args[] = {(void*)&src, (void*)&dst, (void*)&x,
                        (void*)&W1, (void*)&b1, (void*)&W2, (void*)&b2,
                        (void*)&bh, (void*)&bucktot, (void*)&buckbase,
                        (void*)&packed, (void*)&dinv, (void*)&g, (void*)&u,
                        (void*)&out,
                        (void*)&n, (void*)&e, (void*)&nb, (void*)&ec, (void*)&K};
        hipLaunchCooperativeKernel((void*)gcn_all, dim3(G), dim3(TB), args, 0, stream);
    } else {
        float* A = (float*)d_ws;
        float* B = A + n;
        float* C = B + n;
        const int bn = (n + 255) / 256;
        const int be = (e + 255) / 256;
        f_init   <<<bn, 256, 0, stream>>>(A, n);
        f_degree <<<be, 256, 0, stream>>>(dst, A, e);
        f_node1  <<<bn, 256, 0, stream>>>(x, A, B, C, n);
        f_scatter<<<be, 256, 0, stream>>>(src, dst, B, C, e);
        f_node2  <<<bn, 256, 0, stream>>>(A, C, W1, b1, W2, B, C, n, K);
        f_scatter<<<be, 256, 0, stream>>>(src, dst, B, C, e);
        f_out    <<<bn, 256, 0, stream>>>(A, C, b2, out, n);
    }
}

// Round 8
// 58.967 us; speedup vs baseline: 12.7556x; 12.7556x over previous
//
#include <hip/hip_runtime.h>
#include <math.h>

// 2-layer GCN, scalar-per-node form, zero global atomics, 6 dispatches:
//   k_hist   : per-chunk LDS histogram of bucket (dst>>8) -> bh[bucket][chunk]
//   k_colscan: one wave per bucket row (int4 + shfl_up) -> bh ranks, bucktot
//   k_bin    : inline block-scan of bucktot (replaces bscan dispatch);
//              packed[base+rank] = (src<<8)|(dst&255); block0 publishes buckbase
//   k_deg    : per bucket (256 nodes, 512 thr) LDS int hist -> dinv, g = dinv*x
//   k_l1     : per bucket LDS float acc of g[src] -> u = dinv*h2(dinv*(acc+g))
//   k_l2     : per bucket LDS float acc of u[src] -> out = sigmoid(...)
// Round-7 lesson: cooperative grid.sync costs ~100us on gfx950 -> multi-kernel.

#define NBLK 512   // edge-phase blocks; bh row length
#define TBE  256   // edge-phase threads
#define TBA  512   // aggregation-phase threads
#define MAXB 512   // max buckets (256 nodes each): n <= 131072

__device__ __forceinline__ int chunk_of(int blk) {
    // consecutive chunks -> same XCD (dispatch round-robins blk%8 across XCDs)
    return ((blk & 7) * (NBLK >> 3)) + (blk >> 3);
}

__global__ __launch_bounds__(TBE)
void k_hist(const int* __restrict__ dst, int* __restrict__ bh,
            int e, int ec, int nb) {
    __shared__ int sh[MAXB];
    const int t = threadIdx.x;
    const int chunk = chunk_of(blockIdx.x);
    for (int i = t; i < nb; i += TBE) sh[i] = 0;
    __syncthreads();
    int start = chunk * ec, end = min(e, start + ec);
    int tile = start;
    for (; tile + TBE * 4 <= end; tile += TBE * 4) {
        const int4 d4 = *reinterpret_cast<const int4*>(dst + tile + t * 4);
        atomicAdd(&sh[d4.x >> 8], 1);
        atomicAdd(&sh[d4.y >> 8], 1);
        atomicAdd(&sh[d4.z >> 8], 1);
        atomicAdd(&sh[d4.w >> 8], 1);
    }
    for (int i = tile + t; i < end; i += TBE) atomicAdd(&sh[dst[i] >> 8], 1);
    __syncthreads();
    for (int i = t; i < nb; i += TBE) bh[(size_t)i * NBLK + chunk] = sh[i];
}

// One wave per bucket row (512 ints): lane owns 8 contiguous ints (2x int4);
// lane-local prefix + shfl_up wave scan; coalesced row access.
__global__ __launch_bounds__(TBE)
void k_colscan(int* __restrict__ bh, int* __restrict__ bucktot, int nb) {
    const int lane = threadIdx.x & 63;
    const int wid = threadIdx.x >> 6;
    const int b = blockIdx.x * 4 + wid;
    if (b >= nb) return;
    int4* row = reinterpret_cast<int4*>(bh + (size_t)b * NBLK + lane * 8);
    int4 v0 = row[0], v1 = row[1];
    int s = v0.x + v0.y + v0.z + v0.w + v1.x + v1.y + v1.z + v1.w;
    int inc = s;
#pragma unroll
    for (int off = 1; off < 64; off <<= 1) {
        int w = __shfl_up(inc, off, 64);
        if (lane >= off) inc += w;
    }
    int run = inc - s;  // wave-exclusive base for this lane
    int c;
    c = v0.x; v0.x = run; run += c;  c = v0.y; v0.y = run; run += c;
    c = v0.z; v0.z = run; run += c;  c = v0.w; v0.w = run; run += c;
    c = v1.x; v1.x = run; run += c;  c = v1.y; v1.y = run; run += c;
    c = v1.z; v1.z = run; run += c;  c = v1.w; v1.w = run; run += c;
    row[0] = v0; row[1] = v1;
    if (lane == 63) bucktot[b] = inc;
}

__global__ __launch_bounds__(TBE)
void k_bin(const int* __restrict__ src, const int* __restrict__ dst,
           const int* __restrict__ bh, const int* __restrict__ bucktot,
           int* __restrict__ buckbase, int* __restrict__ packed,
           int e, int ec, int nb) {
    __shared__ int sbase[MAXB];   // exclusive bucket bases -> then write cursors
    __shared__ int ssum[TBE];
    const int t = threadIdx.x;
    const int chunk = chunk_of(blockIdx.x);

    // inline exclusive scan of bucktot (every block; ~1us, saves a dispatch)
    int i0 = 2 * t, i1 = 2 * t + 1;
    int c0 = (i0 < nb) ? bucktot[i0] : 0;
    int c1 = (i1 < nb) ? bucktot[i1] : 0;
    int tsum = c0 + c1;
    ssum[t] = tsum;
    __syncthreads();
    for (int off = 1; off < TBE; off <<= 1) {
        int w = (t >= off) ? ssum[t - off] : 0;
        __syncthreads();
        ssum[t] += w;
        __syncthreads();
    }
    int ex = ssum[t] - tsum;
    if (i0 < nb) sbase[i0] = ex;
    if (i1 < nb) sbase[i1] = ex + c0;
    __syncthreads();

    if (blockIdx.x == 0) {   // publish buckbase for deg/l1/l2
        for (int i = t; i < nb; i += TBE) buckbase[i] = sbase[i];
        if (t == 0) buckbase[nb] = e;
    }
    // convert to this chunk's write cursors (in place; same-slot same-thread)
    for (int i = t; i < nb; i += TBE) sbase[i] += bh[(size_t)i * NBLK + chunk];
    __syncthreads();

    int start = chunk * ec, end = min(e, start + ec);
    int tile = start;
    for (; tile + TBE * 4 <= end; tile += TBE * 4) {
        const int4 s4 = *reinterpret_cast<const int4*>(src + tile + t * 4);
        const int4 d4 = *reinterpret_cast<const int4*>(dst + tile + t * 4);
        int p;
        p = atomicAdd(&sbase[d4.x >> 8], 1); packed[p] = (s4.x << 8) | (d4.x & 255);
        p = atomicAdd(&sbase[d4.y >> 8], 1); packed[p] = (s4.y << 8) | (d4.y & 255);
        p = atomicAdd(&sbase[d4.z >> 8], 1); packed[p] = (s4.z << 8) | (d4.z & 255);
        p = atomicAdd(&sbase[d4.w >> 8], 1); packed[p] = (s4.w << 8) | (d4.w & 255);
    }
    for (int i = tile + t; i < end; i += TBE) {
        int d = dst[i], s = src[i];
        int p = atomicAdd(&sbase[d >> 8], 1);
        packed[p] = (s << 8) | (d & 255);
    }
}

__global__ __launch_bounds__(TBA)
void k_deg(const int* __restrict__ packed, const int* __restrict__ buckbase,
           const float* __restrict__ x, float* __restrict__ dinv,
           float* __restrict__ g, int n) {
    __shared__ int cnt[1024];      // 256 nodes x 4 banks
    const int t = threadIdx.x, b = blockIdx.x;
    cnt[t] = 0; cnt[t + 512] = 0;
    __syncthreads();
    const int bank = (t & 3) << 8;
    int s0 = buckbase[b], s1 = buckbase[b + 1];
    for (int j = s0 + t; j < s1; j += TBA)
        atomicAdd(&cnt[bank | (packed[j] & 255)], 1);
    __syncthreads();
    if (t < 256) {
        int node = (b << 8) + t;
        if (node < n) {
            int c = cnt[t] + cnt[256 + t] + cnt[512 + t] + cnt[768 + t];
            float di = rsqrtf(1.0f + (float)c);
            dinv[node] = di;
            g[node] = di * x[node];
        }
    }
}

__global__ __launch_bounds__(TBA)
void k_l1(const int* __restrict__ packed, const int* __restrict__ buckbase,
          const float* __restrict__ g, const float* __restrict__ dinv,
          const float* __restrict__ W1, const float* __restrict__ b1,
          const float* __restrict__ W2, float* __restrict__ u, int n, int K) {
    __shared__ float acc[1024];    // 256 nodes x 4 banks
    const int t = threadIdx.x, b = blockIdx.x;
    acc[t] = 0.f; acc[t + 512] = 0.f;
    __syncthreads();
    const int bank = (t & 3) << 8;
    int s0 = buckbase[b], s1 = buckbase[b + 1];
    for (int j = s0 + t; j < s1; j += TBA) {
        int pk = packed[j];
        atomicAdd(&acc[bank | (pk & 255)], g[pk >> 8]);   // LDS float atomic
    }
    __syncthreads();
    if (t < 256) {
        int node = (b << 8) + t;
        if (node < n) {
            float s = acc[t] + acc[256 + t] + acc[512 + t] + acc[768 + t];
            float di = dinv[node];
            float tt = di * (s + g[node]);
            float h2 = 0.f;
            for (int k = 0; k < K; ++k) {
                float z = fmaf(W1[k], tt, b1[k]);
                h2 = fmaf(__fdividef(1.f, 1.f + __expf(-z)), W2[k], h2);
            }
            u[node] = di * h2;
        }
    }
}

__global__ __launch_bounds__(TBA)
void k_l2(const int* __restrict__ packed, const int* __restrict__ buckbase,
          const float* __restrict__ u, const float* __restrict__ dinv,
          const float* __restrict__ b2, float* __restrict__ out, int n) {
    __shared__ float acc[1024];
    const int t = threadIdx.x, b = blockIdx.x;
    acc[t] = 0.f; acc[t + 512] = 0.f;
    __syncthreads();
    const int bank = (t & 3) << 8;
    int s0 = buckbase[b], s1 = buckbase[b + 1];
    for (int j = s0 + t; j < s1; j += TBA) {
        int pk = packed[j];
        atomicAdd(&acc[bank | (pk & 255)], u[pk >> 8]);
    }
    __syncthreads();
    if (t < 256) {
        int node = (b << 8) + t;
        if (node < n) {
            float s = acc[t] + acc[256 + t] + acc[512 + t] + acc[768 + t];
            float z = fmaf(dinv[node], s + u[node], b2[0]);
            out[node] = __fdividef(1.f, 1.f + __expf(-z));
        }
    }
}

// ---------------- fallback (round-1 atomic path, 3n floats) ----------------
__global__ void f_init(float* __restrict__ deg, int n) {
    int i = blockIdx.x * 256 + threadIdx.x;
    if (i < n) deg[i] = 1.0f;
}
__global__ void f_degree(const int* __restrict__ dst, float* __restrict__ deg, int e) {
    int i = blockIdx.x * 256 + threadIdx.x;
    if (i < e) atomicAdd(&deg[dst[i]], 1.0f);
}
__global__ void f_node1(const float* __restrict__ x, float* dd,
                        float* __restrict__ g, float* __restrict__ s, int n) {
    int i = blockIdx.x * 256 + threadIdx.x;
    if (i < n) {
        float di = rsqrtf(dd[i]);
        dd[i] = di;
        float gi = di * x[i];
        g[i] = gi; s[i] = gi;
    }
}
__global__ void f_scatter(const int* __restrict__ src, const int* __restrict__ dst,
                          const float* __restrict__ g, float* __restrict__ s, int e) {
    int i = blockIdx.x * 256 + threadIdx.x;
    if (i < e) atomicAdd(&s[dst[i]], g[src[i]]);
}
__global__ void f_node2(const float* __restrict__ dinv, const float* s,
                        const float* __restrict__ W1, const float* __restrict__ b1,
                        const float* __restrict__ W2, float* u, float* r, int n, int K) {
    int i = blockIdx.x * 256 + threadIdx.x;
    if (i < n) {
        float tt = dinv[i] * s[i];
        float h2 = 0.f;
        for (int k = 0; k < K; ++k) {
            float z = fmaf(W1[k], tt, b1[k]);
            h2 = fmaf(__fdividef(1.f, 1.f + __expf(-z)), W2[k], h2);
        }
        float ui = dinv[i] * h2;
        u[i] = ui; r[i] = ui;
    }
}
__global__ void f_out(const float* __restrict__ dinv, const float* __restrict__ r,
                      const float* __restrict__ b2, float* __restrict__ out, int n) {
    int i = blockIdx.x * 256 + threadIdx.x;
    if (i < n) {
        float z = fmaf(dinv[i], r[i], b2[0]);
        out[i] = __fdividef(1.f, 1.f + __expf(-z));
    }
}

extern "C" void kernel_launch(void* const* d_in, const int* in_sizes, int n_in,
                              void* d_out, int out_size, void* d_ws, size_t ws_size,
                              hipStream_t stream) {
    const float* x  = (const float*)d_in[0];
    const int*   ei = (const int*)d_in[1];
    const float* W1 = (const float*)d_in[2];
    const float* b1 = (const float*)d_in[3];
    const float* W2 = (const float*)d_in[4];
    const float* b2 = (const float*)d_in[5];

    const int n = in_sizes[0];
    const int e = in_sizes[1] / 2;
    const int K = in_sizes[2];
    const int* src = ei;
    const int* dst = ei + e;
    float* out = (float*)d_out;

    const int nb = (n + 255) >> 8;                     // buckets (256 nodes)
    const int ec = (((e + NBLK - 1) / NBLK) + 3) & ~3; // edges/chunk, mult of 4

    // ws: bh[nb*NBLK] bucktot[nb] buckbase[nb+1] packed[e] dinv[n] g[n] u[n]
    size_t need = ((size_t)nb * NBLK + 2 * (size_t)nb + 1 + (size_t)e + 3 * (size_t)n) * 4;

    if (nb <= MAXB && n < (1 << 23) && (e & 3) == 0 && ws_size >= need) {
        int* bh       = (int*)d_ws;
        int* bucktot  = bh + (size_t)nb * NBLK;
        int* buckbase = bucktot + nb;
        int* packed   = buckbase + nb + 1;
        float* dinv   = (float*)(packed + e);
        float* g      = dinv + n;
        float* u      = g + n;

        k_hist   <<<NBLK, TBE, 0, stream>>>(dst, bh, e, ec, nb);
        k_colscan<<<(nb + 3) / 4, TBE, 0, stream>>>(bh, bucktot, nb);
        k_bin    <<<NBLK, TBE, 0, stream>>>(src, dst, bh, bucktot, buckbase,
                                            packed, e, ec, nb);
        k_deg    <<<nb, TBA, 0, stream>>>(packed, buckbase, x, dinv, g, n);
        k_l1     <<<nb, TBA, 0, stream>>>(packed, buckbase, g, dinv, W1, b1, W2, u, n, K);
        k_l2     <<<nb, TBA, 0, stream>>>(packed, buckbase, u, dinv, b2, out, n);
    } else {
        float* A = (float*)d_ws;
        float* B = A + n;
        float* C = B + n;
        const int bn = (n + 255) / 256;
        const int be = (e + 255) / 256;
        f_init   <<<bn, 256, 0, stream>>>(A, n);
        f_degree <<<be, 256, 0, stream>>>(dst, A, e);
        f_node1  <<<bn, 256, 0, stream>>>(x, A, B, C, n);
        f_scatter<<<be, 256, 0, stream>>>(src, dst, B, C, e);
        f_node2  <<<bn, 256, 0, stream>>>(A, C, W1, b1, W2, B, C, n, K);
        f_scatter<<<be, 256, 0, stream>>>(src, dst, B, C, e);
        f_out    <<<bn, 256, 0, stream>>>(A, C, b2, out, n);
    }
}

// Round 9
// 58.049 us; speedup vs baseline: 12.9573x; 1.0158x over previous
//
#include <hip/hip_runtime.h>
#include <math.h>

// 2-layer GCN, scalar-per-node form, zero global atomics, 6 dispatches:
//   k_hist   : per-chunk LDS histogram of bucket (dst>>8) -> bh[bucket][chunk]
//   k_colscan: one wave per bucket row (int4 + shfl_up) -> bh ranks, bucktot
//   k_bin    : inline WAVE-scan of bucktot (2 barriers, not 16);
//              packed[base+rank] = (src<<8)|(dst&255); block0 publishes buckbase
//   k_deg    : per bucket (256 nodes, 1024 thr) LDS int hist -> dinv, g
//   k_l1     : per bucket LDS float acc of g[src] -> u = dinv*h2(dinv*(acc+g))
//   k_l2     : per bucket LDS float acc of u[src] -> out = sigmoid(...)
// Lessons: r7 coop grid.sync ~110us/sync on gfx950 -> multi-kernel;
//          r1/r2 global atomics 32B write-through each -> zero-atomic sort.

#define NBLK 512   // edge-phase blocks; bh row length
#define TBE  256   // edge-phase threads
#define TBA  1024  // aggregation-phase threads (16 waves, 2 blocks/CU)
#define MAXB 512   // max buckets (256 nodes each): n <= 131072

__device__ __forceinline__ int chunk_of(int blk) {
    // consecutive chunks -> same XCD (dispatch round-robins blk%8 across XCDs)
    return ((blk & 7) * (NBLK >> 3)) + (blk >> 3);
}

__global__ __launch_bounds__(TBE)
void k_hist(const int* __restrict__ dst, int* __restrict__ bh,
            int e, int ec, int nb) {
    __shared__ int sh[MAXB];
    const int t = threadIdx.x;
    const int chunk = chunk_of(blockIdx.x);
    for (int i = t; i < nb; i += TBE) sh[i] = 0;
    __syncthreads();
    int start = chunk * ec, end = min(e, start + ec);
    int tile = start;
    for (; tile + TBE * 4 <= end; tile += TBE * 4) {
        const int4 d4 = *reinterpret_cast<const int4*>(dst + tile + t * 4);
        atomicAdd(&sh[d4.x >> 8], 1);
        atomicAdd(&sh[d4.y >> 8], 1);
        atomicAdd(&sh[d4.z >> 8], 1);
        atomicAdd(&sh[d4.w >> 8], 1);
    }
    for (int i = tile + t; i < end; i += TBE) atomicAdd(&sh[dst[i] >> 8], 1);
    __syncthreads();
    for (int i = t; i < nb; i += TBE) bh[(size_t)i * NBLK + chunk] = sh[i];
}

// One wave per bucket row (512 ints): lane owns 8 contiguous ints (2x int4);
// lane-local prefix + shfl_up wave scan; coalesced row access.
__global__ __launch_bounds__(TBE)
void k_colscan(int* __restrict__ bh, int* __restrict__ bucktot, int nb) {
    const int lane = threadIdx.x & 63;
    const int wid = threadIdx.x >> 6;
    const int b = blockIdx.x * 4 + wid;
    if (b >= nb) return;
    int4* row = reinterpret_cast<int4*>(bh + (size_t)b * NBLK + lane * 8);
    int4 v0 = row[0], v1 = row[1];
    int s = v0.x + v0.y + v0.z + v0.w + v1.x + v1.y + v1.z + v1.w;
    int inc = s;
#pragma unroll
    for (int off = 1; off < 64; off <<= 1) {
        int w = __shfl_up(inc, off, 64);
        if (lane >= off) inc += w;
    }
    int run = inc - s;  // wave-exclusive base for this lane
    int c;
    c = v0.x; v0.x = run; run += c;  c = v0.y; v0.y = run; run += c;
    c = v0.z; v0.z = run; run += c;  c = v0.w; v0.w = run; run += c;
    c = v1.x; v1.x = run; run += c;  c = v1.y; v1.y = run; run += c;
    c = v1.z; v1.z = run; run += c;  c = v1.w; v1.w = run; run += c;
    row[0] = v0; row[1] = v1;
    if (lane == 63) bucktot[b] = inc;
}

__global__ __launch_bounds__(TBE)
void k_bin(const int* __restrict__ src, const int* __restrict__ dst,
           const int* __restrict__ bh, const int* __restrict__ bucktot,
           int* __restrict__ buckbase, int* __restrict__ packed,
           int e, int ec, int nb) {
    __shared__ int sbase[MAXB];   // exclusive bucket bases -> then write cursors
    __shared__ int wtot[4];
    const int t = threadIdx.x;
    const int lane = t & 63, wid = t >> 6;
    const int chunk = chunk_of(blockIdx.x);

    // inline exclusive scan of bucktot: wave-scan + 4-entry combine (2 barriers)
    int i0 = 2 * t, i1 = 2 * t + 1;
    int c0 = (i0 < nb) ? bucktot[i0] : 0;
    int c1 = (i1 < nb) ? bucktot[i1] : 0;
    int tsum = c0 + c1;
    int winc = tsum;
#pragma unroll
    for (int off = 1; off < 64; off <<= 1) {
        int w = __shfl_up(winc, off, 64);
        if (lane >= off) winc += w;
    }
    if (lane == 63) wtot[wid] = winc;
    __syncthreads();
    int wbase = 0;
#pragma unroll
    for (int w = 0; w < 4; ++w) wbase += (w < wid) ? wtot[w] : 0;
    int ex = wbase + winc - tsum;
    if (i0 < nb) sbase[i0] = ex;
    if (i1 < nb) sbase[i1] = ex + c0;
    __syncthreads();

    if (blockIdx.x == 0) {   // publish buckbase for deg/l1/l2
        for (int i = t; i < nb; i += TBE) buckbase[i] = sbase[i];
        if (t == 0) buckbase[nb] = e;
    }
    // convert to this chunk's write cursors (same thread per slot, no race)
    for (int i = t; i < nb; i += TBE) sbase[i] += bh[(size_t)i * NBLK + chunk];
    __syncthreads();

    int start = chunk * ec, end = min(e, start + ec);
    int tile = start;
    for (; tile + TBE * 4 <= end; tile += TBE * 4) {
        const int4 s4 = *reinterpret_cast<const int4*>(src + tile + t * 4);
        const int4 d4 = *reinterpret_cast<const int4*>(dst + tile + t * 4);
        int p;
        p = atomicAdd(&sbase[d4.x >> 8], 1); packed[p] = (s4.x << 8) | (d4.x & 255);
        p = atomicAdd(&sbase[d4.y >> 8], 1); packed[p] = (s4.y << 8) | (d4.y & 255);
        p = atomicAdd(&sbase[d4.z >> 8], 1); packed[p] = (s4.z << 8) | (d4.z & 255);
        p = atomicAdd(&sbase[d4.w >> 8], 1); packed[p] = (s4.w << 8) | (d4.w & 255);
    }
    for (int i = tile + t; i < end; i += TBE) {
        int d = dst[i], s = src[i];
        int p = atomicAdd(&sbase[d >> 8], 1);
        packed[p] = (s << 8) | (d & 255);
    }
}

// Vectorized segment walk: scalar head to 16B alignment, int4 body, scalar tail.
#define SEG_WALK(S0, S1, BODY_PK)                                        \
    {                                                                    \
        int head = min((S1), ((S0) + 3) & ~3);                           \
        for (int j = (S0) + t; j < head; j += TBA) {                     \
            int pk = packed[j]; BODY_PK;                                 \
        }                                                                \
        int nvec = ((S1) - head) >> 2;                                   \
        const int4* pv = reinterpret_cast<const int4*>(packed + head);   \
        for (int j = t; j < nvec; j += TBA) {                            \
            int4 q = pv[j];                                              \
            { int pk = q.x; BODY_PK; }                                   \
            { int pk = q.y; BODY_PK; }                                   \
            { int pk = q.z; BODY_PK; }                                   \
            { int pk = q.w; BODY_PK; }                                   \
        }                                                                \
        for (int j = head + 4 * nvec + t; j < (S1); j += TBA) {          \
            int pk = packed[j]; BODY_PK;                                 \
        }                                                                \
    }

__global__ __launch_bounds__(TBA)
void k_deg(const int* __restrict__ packed, const int* __restrict__ buckbase,
           const float* __restrict__ x, float* __restrict__ dinv,
           float* __restrict__ g, int n) {
    __shared__ int cnt[1024];      // 256 nodes x 4 banks
    const int t = threadIdx.x, b = blockIdx.x;
    cnt[t] = 0;
    __syncthreads();
    const int bank = (t & 3) << 8;
    int s0 = buckbase[b], s1 = buckbase[b + 1];
    SEG_WALK(s0, s1, atomicAdd(&cnt[bank | (pk & 255)], 1))
    __syncthreads();
    if (t < 256) {
        int node = (b << 8) + t;
        if (node < n) {
            int c = cnt[t] + cnt[256 + t] + cnt[512 + t] + cnt[768 + t];
            float di = rsqrtf(1.0f + (float)c);
            dinv[node] = di;
            g[node] = di * x[node];
        }
    }
}

__global__ __launch_bounds__(TBA)
void k_l1(const int* __restrict__ packed, const int* __restrict__ buckbase,
          const float* __restrict__ g, const float* __restrict__ dinv,
          const float* __restrict__ W1, const float* __restrict__ b1,
          const float* __restrict__ W2, float* __restrict__ u, int n, int K) {
    __shared__ float acc[1024];    // 256 nodes x 4 banks
    const int t = threadIdx.x, b = blockIdx.x;
    acc[t] = 0.f;
    __syncthreads();
    const int bank = (t & 3) << 8;
    int s0 = buckbase[b], s1 = buckbase[b + 1];
    SEG_WALK(s0, s1, atomicAdd(&acc[bank | (pk & 255)], g[pk >> 8]))
    __syncthreads();
    if (t < 256) {
        int node = (b << 8) + t;
        if (node < n) {
            float s = acc[t] + acc[256 + t] + acc[512 + t] + acc[768 + t];
            float di = dinv[node];
            float tt = di * (s + g[node]);
            float h2 = 0.f;
            for (int k = 0; k < K; ++k) {
                float z = fmaf(W1[k], tt, b1[k]);
                h2 = fmaf(__fdividef(1.f, 1.f + __expf(-z)), W2[k], h2);
            }
            u[node] = di * h2;
        }
    }
}

__global__ __launch_bounds__(TBA)
void k_l2(const int* __restrict__ packed, const int* __restrict__ buckbase,
          const float* __restrict__ u, const float* __restrict__ dinv,
          const float* __restrict__ b2, float* __restrict__ out, int n) {
    __shared__ float acc[1024];
    const int t = threadIdx.x, b = blockIdx.x;
    acc[t] = 0.f;
    __syncthreads();
    const int bank = (t & 3) << 8;
    int s0 = buckbase[b], s1 = buckbase[b + 1];
    SEG_WALK(s0, s1, atomicAdd(&acc[bank | (pk & 255)], u[pk >> 8]))
    __syncthreads();
    if (t < 256) {
        int node = (b << 8) + t;
        if (node < n) {
            float s = acc[t] + acc[256 + t] + acc[512 + t] + acc[768 + t];
            float z = fmaf(dinv[node], s + u[node], b2[0]);
            out[node] = __fdividef(1.f, 1.f + __expf(-z));
        }
    }
}

// ---------------- fallback (round-1 atomic path, 3n floats) ----------------
__global__ void f_init(float* __restrict__ deg, int n) {
    int i = blockIdx.x * 256 + threadIdx.x;
    if (i < n) deg[i] = 1.0f;
}
__global__ void f_degree(const int* __restrict__ dst, float* __restrict__ deg, int e) {
    int i = blockIdx.x * 256 + threadIdx.x;
    if (i < e) atomicAdd(&deg[dst[i]], 1.0f);
}
__global__ void f_node1(const float* __restrict__ x, float* dd,
                        float* __restrict__ g, float* __restrict__ s, int n) {
    int i = blockIdx.x * 256 + threadIdx.x;
    if (i < n) {
        float di = rsqrtf(dd[i]);
        dd[i] = di;
        float gi = di * x[i];
        g[i] = gi; s[i] = gi;
    }
}
__global__ void f_scatter(const int* __restrict__ src, const int* __restrict__ dst,
                          const float* __restrict__ g, float* __restrict__ s, int e) {
    int i = blockIdx.x * 256 + threadIdx.x;
    if (i < e) atomicAdd(&s[dst[i]], g[src[i]]);
}
__global__ void f_node2(const float* __restrict__ dinv, const float* s,
                        const float* __restrict__ W1, const float* __restrict__ b1,
                        const float* __restrict__ W2, float* u, float* r, int n, int K) {
    int i = blockIdx.x * 256 + threadIdx.x;
    if (i < n) {
        float tt = dinv[i] * s[i];
        float h2 = 0.f;
        for (int k = 0; k < K; ++k) {
            float z = fmaf(W1[k], tt, b1[k]);
            h2 = fmaf(__fdividef(1.f, 1.f + __expf(-z)), W2[k], h2);
        }
        float ui = dinv[i] * h2;
        u[i] = ui; r[i] = ui;
    }
}
__global__ void f_out(const float* __restrict__ dinv, const float* __restrict__ r,
                      const float* __restrict__ b2, float* __restrict__ out, int n) {
    int i = blockIdx.x * 256 + threadIdx.x;
    if (i < n) {
        float z = fmaf(dinv[i], r[i], b2[0]);
        out[i] = __fdividef(1.f, 1.f + __expf(-z));
    }
}

extern "C" void kernel_launch(void* const* d_in, const int* in_sizes, int n_in,
                              void* d_out, int out_size, void* d_ws, size_t ws_size,
                              hipStream_t stream) {
    const float* x  = (const float*)d_in[0];
    const int*   ei = (const int*)d_in[1];
    const float* W1 = (const float*)d_in[2];
    const float* b1 = (const float*)d_in[3];
    const float* W2 = (const float*)d_in[4];
    const float* b2 = (const float*)d_in[5];

    const int n = in_sizes[0];
    const int e = in_sizes[1] / 2;
    const int K = in_sizes[2];
    const int* src = ei;
    const int* dst = ei + e;
    float* out = (float*)d_out;

    const int nb = (n + 255) >> 8;                     // buckets (256 nodes)
    const int ec = (((e + NBLK - 1) / NBLK) + 3) & ~3; // edges/chunk, mult of 4

    // ws: bh[nb*NBLK] bucktot[nb] buckbase[nb+1] packed[e] dinv[n] g[n] u[n]
    size_t need = ((size_t)nb * NBLK + 2 * (size_t)nb + 1 + (size_t)e + 3 * (size_t)n) * 4;

    if (nb <= MAXB && n < (1 << 23) && (e & 3) == 0 && ws_size >= need) {
        int* bh       = (int*)d_ws;
        int* bucktot  = bh + (size_t)nb * NBLK;
        int* buckbase = bucktot + nb;
        int* packed   = buckbase + nb + 1;
        float* dinv   = (float*)(packed + e);
        float* g      = dinv + n;
        float* u      = g + n;

        k_hist   <<<NBLK, TBE, 0, stream>>>(dst, bh, e, ec, nb);
        k_colscan<<<(nb + 3) / 4, TBE, 0, stream>>>(bh, bucktot, nb);
        k_bin    <<<NBLK, TBE, 0, stream>>>(src, dst, bh, bucktot, buckbase,
                                            packed, e, ec, nb);
        k_deg    <<<nb, TBA, 0, stream>>>(packed, buckbase, x, dinv, g, n);
        k_l1     <<<nb, TBA, 0, stream>>>(packed, buckbase, g, dinv, W1, b1, W2, u, n, K);
        k_l2     <<<nb, TBA, 0, stream>>>(packed, buckbase, u, dinv, b2, out, n);
    } else {
        float* A = (float*)d_ws;
        float* B = A + n;
        float* C = B + n;
        const int bn = (n + 255) / 256;
        const int be = (e + 255) / 256;
        f_init   <<<bn, 256, 0, stream>>>(A, n);
        f_degree <<<be, 256, 0, stream>>>(dst, A, e);
        f_node1  <<<bn, 256, 0, stream>>>(x, A, B, C, n);
        f_scatter<<<be, 256, 0, stream>>>(src, dst, B, C, e);
        f_node2  <<<bn, 256, 0, stream>>>(A, C, W1, b1, W2, B, C, n, K);
        f_scatter<<<be, 256, 0, stream>>>(src, dst, B, C, e);
        f_out    <<<bn, 256, 0, stream>>>(A, C, b2, out, n);
    }
}